// Round 1
// baseline (7310.950 us; speedup 1.0000x reference)
//
#include <hip/hip_runtime.h>

// BeliefPropagation: N=50k nodes, E=1.6M directed edges (2*800k), q=8, 10 iters.
// Per iter: scatter log1p(msg*ew) into node_logprod[dst]; msg update reads
// node_logprod[src] and recomputes log_src at rev[e]=(e±M) (contiguous read,
// avoids materializing log_src); psi + field h fused reduction.

constexpr int Q = 8;
constexpr int NITER = 10;
constexpr int TB = 256;

// ---- setup: ew[e] = exp(beta*attr[e]) - 1 ; deg[dst[e]] += 1 ----
__global__ void ew_deg_kernel(const float* __restrict__ edge_attr,
                              const int* __restrict__ dst,
                              const float* __restrict__ beta_p,
                              float* __restrict__ ew,
                              float* __restrict__ deg,
                              int E) {
    int e = blockIdx.x * TB + threadIdx.x;
    if (e >= E) return;
    float beta = *beta_p;
    ew[e] = expf(beta * edge_attr[e]) - 1.0f;
    atomicAdd(&deg[dst[e]], 1.0f);
}

// ---- scatter: nlp[dst[e], k] += log1p(msg[e,k] * ew[e]) ----
__global__ void scatter_kernel(const float* __restrict__ msg,
                               const float* __restrict__ ew,
                               const int* __restrict__ dst,
                               float* __restrict__ nlp,
                               int E) {
    int e = blockIdx.x * TB + threadIdx.x;
    if (e >= E) return;
    float w = ew[e];
    const float4* mp = reinterpret_cast<const float4*>(msg + (size_t)e * Q);
    float4 m0 = mp[0], m1 = mp[1];
    float ls[Q];
    ls[0] = log1pf(m0.x * w); ls[1] = log1pf(m0.y * w);
    ls[2] = log1pf(m0.z * w); ls[3] = log1pf(m0.w * w);
    ls[4] = log1pf(m1.x * w); ls[5] = log1pf(m1.y * w);
    ls[6] = log1pf(m1.z * w); ls[7] = log1pf(m1.w * w);
    float* base = nlp + (size_t)dst[e] * Q;
#pragma unroll
    for (int k = 0; k < Q; ++k) atomicAdd(base + k, ls[k]);
}

// ---- msg update: new_msg[e] = norm(exp(h + nlp[src[e]] - log1p(msg[rev]*ew[rev]))) ----
__global__ void msg_kernel(const float* __restrict__ msg_old,
                           const float* __restrict__ ew,
                           const int* __restrict__ src,
                           const float* __restrict__ nlp,
                           const float* __restrict__ h,
                           float* __restrict__ msg_new,
                           int E, int M) {
    int e = blockIdx.x * TB + threadIdx.x;
    if (e >= E) return;
    int re = (e < M) ? (e + M) : (e - M);
    float w = ew[re];
    const float4* mp = reinterpret_cast<const float4*>(msg_old + (size_t)re * Q);
    float4 m0 = mp[0], m1 = mp[1];
    const float4* np = reinterpret_cast<const float4*>(nlp + (size_t)src[e] * Q);
    float4 n0 = np[0], n1 = np[1];
    const float4* hp = reinterpret_cast<const float4*>(h);
    float4 h0 = hp[0], h1 = hp[1];

    float t[Q];
    t[0] = expf(h0.x + n0.x - log1pf(m0.x * w));
    t[1] = expf(h0.y + n0.y - log1pf(m0.y * w));
    t[2] = expf(h0.z + n0.z - log1pf(m0.z * w));
    t[3] = expf(h0.w + n0.w - log1pf(m0.w * w));
    t[4] = expf(h1.x + n1.x - log1pf(m1.x * w));
    t[5] = expf(h1.y + n1.y - log1pf(m1.y * w));
    t[6] = expf(h1.z + n1.z - log1pf(m1.z * w));
    t[7] = expf(h1.w + n1.w - log1pf(m1.w * w));

    float s = 0.f;
#pragma unroll
    for (int k = 0; k < Q; ++k) s += t[k];
    float inv = 1.0f / s;
    float4 o0 = make_float4(t[0]*inv, t[1]*inv, t[2]*inv, t[3]*inv);
    float4 o1 = make_float4(t[4]*inv, t[5]*inv, t[6]*inv, t[7]*inv);
    float4* op = reinterpret_cast<float4*>(msg_new + (size_t)e * Q);
    op[0] = o0; op[1] = o1;
}

// ---- psi: new_psi = norm(exp(h + nlp[n])); fused field accumulation deg[n]*psi ----
__global__ void psi_kernel(const float* __restrict__ nlp,
                           const float* __restrict__ h,
                           const float* __restrict__ deg,
                           float* __restrict__ psi_out,
                           float* __restrict__ h_accum,
                           int N) {
    __shared__ float acc[Q];
    if (threadIdx.x < Q) acc[threadIdx.x] = 0.f;
    __syncthreads();
    int n = blockIdx.x * TB + threadIdx.x;
    float contrib[Q];
#pragma unroll
    for (int k = 0; k < Q; ++k) contrib[k] = 0.f;
    if (n < N) {
        const float4* np = reinterpret_cast<const float4*>(nlp + (size_t)n * Q);
        float4 n0 = np[0], n1 = np[1];
        const float4* hp = reinterpret_cast<const float4*>(h);
        float4 h0 = hp[0], h1 = hp[1];
        float p[Q];
        p[0] = expf(h0.x + n0.x); p[1] = expf(h0.y + n0.y);
        p[2] = expf(h0.z + n0.z); p[3] = expf(h0.w + n0.w);
        p[4] = expf(h1.x + n1.x); p[5] = expf(h1.y + n1.y);
        p[6] = expf(h1.z + n1.z); p[7] = expf(h1.w + n1.w);
        float s = 0.f;
#pragma unroll
        for (int k = 0; k < Q; ++k) s += p[k];
        float inv = 1.0f / s;
#pragma unroll
        for (int k = 0; k < Q; ++k) p[k] *= inv;
        float4* op = reinterpret_cast<float4*>(psi_out + (size_t)n * Q);
        op[0] = make_float4(p[0], p[1], p[2], p[3]);
        op[1] = make_float4(p[4], p[5], p[6], p[7]);
        float d = deg[n];
#pragma unroll
        for (int k = 0; k < Q; ++k) contrib[k] = d * p[k];
    }
    // wave (64-lane) shuffle reduce, then LDS, then one global atomic per k per block
#pragma unroll
    for (int k = 0; k < Q; ++k) {
        float v = contrib[k];
#pragma unroll
        for (int off = 32; off > 0; off >>= 1) v += __shfl_down(v, off);
        if ((threadIdx.x & 63) == 0) atomicAdd(&acc[k], v);
    }
    __syncthreads();
    if (threadIdx.x < Q) atomicAdd(&h_accum[threadIdx.x], acc[threadIdx.x]);
}

// ---- field of psi_init (h0 bootstrap): accumulate deg[n]*psi[n,k] ----
__global__ void field_kernel(const float* __restrict__ psi,
                             const float* __restrict__ deg,
                             float* __restrict__ h_accum,
                             int N) {
    __shared__ float acc[Q];
    if (threadIdx.x < Q) acc[threadIdx.x] = 0.f;
    __syncthreads();
    int n = blockIdx.x * TB + threadIdx.x;
    float contrib[Q];
#pragma unroll
    for (int k = 0; k < Q; ++k) contrib[k] = 0.f;
    if (n < N) {
        const float4* pp = reinterpret_cast<const float4*>(psi + (size_t)n * Q);
        float4 p0 = pp[0], p1 = pp[1];
        float d = deg[n];
        contrib[0] = d * p0.x; contrib[1] = d * p0.y;
        contrib[2] = d * p0.z; contrib[3] = d * p0.w;
        contrib[4] = d * p1.x; contrib[5] = d * p1.y;
        contrib[6] = d * p1.z; contrib[7] = d * p1.w;
    }
#pragma unroll
    for (int k = 0; k < Q; ++k) {
        float v = contrib[k];
#pragma unroll
        for (int off = 32; off > 0; off >>= 1) v += __shfl_down(v, off);
        if ((threadIdx.x & 63) == 0) atomicAdd(&acc[k], v);
    }
    __syncthreads();
    if (threadIdx.x < Q) atomicAdd(&h_accum[threadIdx.x], acc[threadIdx.x]);
}

// ---- h[k] = -(beta/N) * h_accum[k]; h_accum[k] = 0 ----
__global__ void finalize_h_kernel(const float* __restrict__ beta_p,
                                  float* __restrict__ h,
                                  float* __restrict__ h_accum,
                                  float invN) {
    int k = threadIdx.x;
    if (k < Q) {
        float beta = *beta_p;
        h[k] = -beta * invN * h_accum[k];
        h_accum[k] = 0.f;
    }
}

extern "C" void kernel_launch(void* const* d_in, const int* in_sizes, int n_in,
                              void* d_out, int out_size, void* d_ws, size_t ws_size,
                              hipStream_t stream) {
    const int*   edge_index = (const int*)d_in[0];
    const float* edge_attr  = (const float*)d_in[1];
    const float* msg_init   = (const float*)d_in[2];
    const float* psi_init   = (const float*)d_in[3];
    const float* beta_p     = (const float*)d_in[4];

    const int E = in_sizes[1];      // 1,600,000
    const int M = E / 2;
    const int N = in_sizes[3] / Q;  // 50,000

    const int* src = edge_index;       // row 0
    const int* dst = edge_index + E;   // row 1

    float* out_msg = (float*)d_out;
    float* out_psi = (float*)d_out + (size_t)E * Q;

    // workspace carve-up (256B aligned)
    char* ws = (char*)d_ws;
    size_t off = 0;
    auto alloc = [&](size_t bytes) -> float* {
        float* p = (float*)(ws + off);
        off = (off + bytes + 255) & ~(size_t)255;
        return p;
    };
    float* ws_msg  = alloc((size_t)E * Q * sizeof(float));  // 51.2 MB
    float* ew      = alloc((size_t)E * sizeof(float));      // 6.4 MB
    float* nlp     = alloc((size_t)N * Q * sizeof(float));  // 1.6 MB
    float* deg     = alloc((size_t)N * sizeof(float));      // 0.2 MB
    float* h       = alloc(Q * sizeof(float));
    float* h_accum = alloc(Q * sizeof(float));
    (void)ws_size;

    const int gE = (E + TB - 1) / TB;
    const int gN = (N + TB - 1) / TB;
    const float invN = 1.0f / (float)N;

    // zero deg + h_accum
    hipMemsetAsync(deg, 0, (size_t)N * sizeof(float), stream);
    hipMemsetAsync(h_accum, 0, Q * sizeof(float), stream);

    // setup: ew, deg, h0
    ew_deg_kernel<<<gE, TB, 0, stream>>>(edge_attr, dst, beta_p, ew, deg, E);
    field_kernel<<<gN, TB, 0, stream>>>(psi_init, deg, h_accum, N);
    finalize_h_kernel<<<1, 64, 0, stream>>>(beta_p, h, h_accum, invN);

    const float* cur = msg_init;
    for (int t = 0; t < NITER; ++t) {
        float* wmsg = (t & 1) ? out_msg : ws_msg;  // iter 9 (odd) -> d_out
        hipMemsetAsync(nlp, 0, (size_t)N * Q * sizeof(float), stream);
        scatter_kernel<<<gE, TB, 0, stream>>>(cur, ew, dst, nlp, E);
        msg_kernel<<<gE, TB, 0, stream>>>(cur, ew, src, nlp, h, wmsg, E, M);
        psi_kernel<<<gN, TB, 0, stream>>>(nlp, h, deg, out_psi, h_accum, N);
        finalize_h_kernel<<<1, 64, 0, stream>>>(beta_p, h, h_accum, invN);
        cur = wmsg;
    }
}

// Round 2
// 2219.829 us; speedup vs baseline: 3.2935x; 3.2935x over previous
//
#include <hip/hip_runtime.h>

// BeliefPropagation: N=50k nodes, E=1.6M directed edges (2*800k), q=8, 10 iters.
// R1 change: per-iter scatter-atomics (400MB/iter HBM write-through, 90% of time)
// replaced by one-time CSR build + node-parallel gather (8 lanes/node, one per k).
// psi + field h accumulation fused into the gather kernel.

constexpr int Q = 8;
constexpr int NITER = 10;
constexpr int TB = 256;

// ---- one-time: in-degree histogram ----
__global__ void hist_kernel(const int* __restrict__ dst, int* __restrict__ count, int E) {
    int e = blockIdx.x * TB + threadIdx.x;
    if (e < E) atomicAdd(&count[dst[e]], 1);
}

// ---- one-time: exclusive scan (single block, 1024 threads) ----
__global__ void scan_kernel(const int* __restrict__ count, int* __restrict__ row_start, int N) {
    __shared__ int sums[1024];
    int tid = threadIdx.x;
    int chunk = (N + 1023) >> 10;
    int lo = min(tid * chunk, N), hi = min(lo + chunk, N);
    int s = 0;
    for (int i = lo; i < hi; ++i) s += count[i];
    sums[tid] = s;
    __syncthreads();
    for (int off = 1; off < 1024; off <<= 1) {
        int add = (tid >= off) ? sums[tid - off] : 0;
        __syncthreads();
        sums[tid] += add;
        __syncthreads();
    }
    int run = (tid > 0) ? sums[tid - 1] : 0;
    for (int i = lo; i < hi; ++i) { row_start[i] = run; run += count[i]; }
    if (tid == 1023) row_start[N] = sums[1023];
}

// ---- one-time: fill CSR edge-id list ----
__global__ void fill_kernel(const int* __restrict__ dst, int* __restrict__ cursor,
                            int* __restrict__ csr_eid, int E) {
    int e = blockIdx.x * TB + threadIdx.x;
    if (e < E) {
        int p = atomicAdd(&cursor[dst[e]], 1);
        csr_eid[p] = e;
    }
}

// ---- bootstrap field: h_accum[k] += deg[n] * psi_init[n,k] ----
__global__ void field_kernel(const float* __restrict__ psi,
                             const int* __restrict__ row_start,
                             float* __restrict__ h_accum, int N) {
    int t = blockIdx.x * TB + threadIdx.x;
    int n = t >> 3, k = t & 7;
    float contrib = 0.f;
    if (n < N) {
        float d = (float)(row_start[n + 1] - row_start[n]);
        contrib = d * psi[(size_t)n * Q + k];
    }
    contrib += __shfl_xor(contrib, 8);
    contrib += __shfl_xor(contrib, 16);
    contrib += __shfl_xor(contrib, 32);
    if ((threadIdx.x & 63) < Q) atomicAdd(&h_accum[threadIdx.x & 7], contrib);
}

// ---- per-iter: gather nlp[n,k] = sum_in log1p(msg*ew); fused psi + field accum ----
__global__ void gather_psi_kernel(const float* __restrict__ msg,
                                  const float* __restrict__ edge_attr,
                                  const float* __restrict__ beta_p,
                                  const int* __restrict__ row_start,
                                  const int* __restrict__ csr_eid,
                                  const float* __restrict__ h,
                                  float* __restrict__ nlp,
                                  float* __restrict__ psi_out,
                                  float* __restrict__ h_accum,
                                  int N) {
    int t = blockIdx.x * TB + threadIdx.x;
    int n = t >> 3, k = t & 7;
    float contrib = 0.f;
    if (n < N) {
        float beta = *beta_p;
        int lo = row_start[n], hi = row_start[n + 1];
        float acc = 0.f;
        for (int i = lo; i < hi; ++i) {
            int e = csr_eid[i];
            float w = expf(beta * edge_attr[e]) - 1.0f;
            acc += log1pf(msg[(size_t)e * Q + k] * w);
        }
        nlp[(size_t)n * Q + k] = acc;
        // psi: softmax over the 8 lanes of this octet
        float p = expf(h[k] + acc);
        float s = p;
        s += __shfl_xor(s, 1);
        s += __shfl_xor(s, 2);
        s += __shfl_xor(s, 4);
        p /= s;
        psi_out[(size_t)n * Q + k] = p;
        contrib = (float)(hi - lo) * p;
    }
    // reduce contrib across octets of the wave (per k), lanes 0..7 hold per-k sums
    contrib += __shfl_xor(contrib, 8);
    contrib += __shfl_xor(contrib, 16);
    contrib += __shfl_xor(contrib, 32);
    if ((threadIdx.x & 63) < Q) atomicAdd(&h_accum[threadIdx.x & 7], contrib);
}

// ---- per-iter: new_msg[e] = norm(exp(h + nlp[src[e]] - log1p(msg[rev]*ew[rev]))) ----
__global__ void msg_kernel(const float* __restrict__ msg_old,
                           const float* __restrict__ edge_attr,
                           const float* __restrict__ beta_p,
                           const int* __restrict__ src,
                           const float* __restrict__ nlp,
                           const float* __restrict__ h,
                           float* __restrict__ msg_new,
                           int E, int M) {
    int e = blockIdx.x * TB + threadIdx.x;
    if (e >= E) return;
    int re = (e < M) ? (e + M) : (e - M);
    float beta = *beta_p;
    float w = expf(beta * edge_attr[re]) - 1.0f;
    const float4* mp = reinterpret_cast<const float4*>(msg_old + (size_t)re * Q);
    float4 m0 = mp[0], m1 = mp[1];
    const float4* np = reinterpret_cast<const float4*>(nlp + (size_t)src[e] * Q);
    float4 n0 = np[0], n1 = np[1];
    const float4* hp = reinterpret_cast<const float4*>(h);
    float4 h0 = hp[0], h1 = hp[1];

    float t[Q];
    t[0] = expf(h0.x + n0.x - log1pf(m0.x * w));
    t[1] = expf(h0.y + n0.y - log1pf(m0.y * w));
    t[2] = expf(h0.z + n0.z - log1pf(m0.z * w));
    t[3] = expf(h0.w + n0.w - log1pf(m0.w * w));
    t[4] = expf(h1.x + n1.x - log1pf(m1.x * w));
    t[5] = expf(h1.y + n1.y - log1pf(m1.y * w));
    t[6] = expf(h1.z + n1.z - log1pf(m1.z * w));
    t[7] = expf(h1.w + n1.w - log1pf(m1.w * w));

    float s = 0.f;
#pragma unroll
    for (int k = 0; k < Q; ++k) s += t[k];
    float inv = 1.0f / s;
    float4* op = reinterpret_cast<float4*>(msg_new + (size_t)e * Q);
    op[0] = make_float4(t[0]*inv, t[1]*inv, t[2]*inv, t[3]*inv);
    op[1] = make_float4(t[4]*inv, t[5]*inv, t[6]*inv, t[7]*inv);
}

// ---- h[k] = -(beta/N) * h_accum[k]; reset h_accum ----
__global__ void finalize_h_kernel(const float* __restrict__ beta_p,
                                  float* __restrict__ h,
                                  float* __restrict__ h_accum,
                                  float invN) {
    int k = threadIdx.x;
    if (k < Q) {
        float beta = *beta_p;
        h[k] = -beta * invN * h_accum[k];
        h_accum[k] = 0.f;
    }
}

extern "C" void kernel_launch(void* const* d_in, const int* in_sizes, int n_in,
                              void* d_out, int out_size, void* d_ws, size_t ws_size,
                              hipStream_t stream) {
    const int*   edge_index = (const int*)d_in[0];
    const float* edge_attr  = (const float*)d_in[1];
    const float* msg_init   = (const float*)d_in[2];
    const float* psi_init   = (const float*)d_in[3];
    const float* beta_p     = (const float*)d_in[4];

    const int E = in_sizes[1];      // 1,600,000
    const int M = E / 2;
    const int N = in_sizes[3] / Q;  // 50,000

    const int* src = edge_index;       // row 0
    const int* dst = edge_index + E;   // row 1

    float* out_msg = (float*)d_out;
    float* out_psi = (float*)d_out + (size_t)E * Q;

    // workspace carve-up (256B aligned)
    char* ws = (char*)d_ws;
    size_t off = 0;
    auto alloc = [&](size_t bytes) -> void* {
        void* p = (void*)(ws + off);
        off = (off + bytes + 255) & ~(size_t)255;
        return p;
    };
    float* ws_msg    = (float*)alloc((size_t)E * Q * sizeof(float));   // 51.2 MB
    int*   csr_eid   = (int*)alloc((size_t)E * sizeof(int));           // 6.4 MB
    float* nlp       = (float*)alloc((size_t)N * Q * sizeof(float));   // 1.6 MB
    int*   row_start = (int*)alloc((size_t)(N + 1) * sizeof(int));     // 0.2 MB
    float* h         = (float*)alloc(Q * sizeof(float));
    float* h_accum   = (float*)alloc(Q * sizeof(float));
    // setup-only arrays alias the nlp region (used before first gather)
    int* count  = (int*)nlp;
    int* cursor = count + N;
    (void)ws_size;

    const int gE   = (E + TB - 1) / TB;
    const int gOct = (N * Q + TB - 1) / TB;
    const float invN = 1.0f / (float)N;

    // ---- setup: CSR build + h0 ----
    hipMemsetAsync(count, 0, (size_t)N * sizeof(int), stream);
    hipMemsetAsync(h_accum, 0, Q * sizeof(float), stream);
    hist_kernel<<<gE, TB, 0, stream>>>(dst, count, E);
    scan_kernel<<<1, 1024, 0, stream>>>(count, row_start, N);
    hipMemcpyAsync(cursor, row_start, (size_t)N * sizeof(int),
                   hipMemcpyDeviceToDevice, stream);
    fill_kernel<<<gE, TB, 0, stream>>>(dst, cursor, csr_eid, E);
    field_kernel<<<gOct, TB, 0, stream>>>(psi_init, row_start, h_accum, N);
    finalize_h_kernel<<<1, 64, 0, stream>>>(beta_p, h, h_accum, invN);

    // ---- 10 BP iterations ----
    const float* cur = msg_init;
    for (int t = 0; t < NITER; ++t) {
        float* wmsg = (t & 1) ? out_msg : ws_msg;  // iter 9 (odd) -> d_out
        gather_psi_kernel<<<gOct, TB, 0, stream>>>(cur, edge_attr, beta_p, row_start,
                                                   csr_eid, h, nlp, out_psi, h_accum, N);
        msg_kernel<<<gE, TB, 0, stream>>>(cur, edge_attr, beta_p, src, nlp, h, wmsg, E, M);
        finalize_h_kernel<<<1, 64, 0, stream>>>(beta_p, h, h_accum, invN);
        cur = wmsg;
    }
}